// Round 7
// baseline (123.446 us; speedup 1.0000x reference)
//
#include <hip/hip_runtime.h>

#define N_SAMP 1024
#define XD     128
#define HID    256

// ---------------------------------------------------------------------------
// Workspace layout (float indices):
//   [0, 1024)            S       per-i sum of exp(T1[i,j]) over j
//   [1024]               T0sum   sum over i of T1[i,i]  (diagonal, sans b2)
//   [1025]               ticket counter (uint bits), last-block-done
//   [2048, 2048+256K)    xpbT    (x @ W1x + b1)^T   [HID][N]  (k-major)
//   [next 256K)          ypT     (y @ W1y)^T        [HID][N]  (k-major)
// S/T0sum/ticket zeroed by gemm_xy every launch (ws is poisoned 0xAA).
// ---------------------------------------------------------------------------

// Kernel 1: the two small GEMMs, writing TRANSPOSED outputs. Thread k owns
// hidden unit k for 4 consecutive rows -> in k-major layout those 4 results
// are contiguous: one float4 store per array. Also zeroes S/T0sum/ticket.
__global__ __launch_bounds__(256) void gemm_xy(
    const float* __restrict__ x, const float* __restrict__ y,
    const float* __restrict__ W1, const float* __restrict__ b1,
    float* __restrict__ xpbT, float* __restrict__ ypT,
    float* __restrict__ S, float* __restrict__ T0sum)
{
    const int k  = threadIdx.x;        // hidden unit 0..255
    const int r0 = blockIdx.x * 4;     // 4 rows per block

    // Zero accumulators (256 blocks x 4 = 1024 S entries; block 0: T0+ticket).
    if (threadIdx.x < 4) S[blockIdx.x * 4 + threadIdx.x] = 0.f;
    if (blockIdx.x == 0 && threadIdx.x == 4) T0sum[0] = 0.f;
    if (blockIdx.x == 0 && threadIdx.x == 5) ((unsigned*)T0sum)[1] = 0u;

    float ax0 = 0.f, ax1 = 0.f, ax2 = 0.f, ax3 = 0.f;
    float ay0 = 0.f, ay1 = 0.f, ay2 = 0.f, ay3 = 0.f;

    #pragma unroll 4
    for (int d = 0; d < XD; ++d) {
        const float wx = W1[d * HID + k];            // coalesced over k
        const float wy = W1[(XD + d) * HID + k];
        ax0 = fmaf(x[(r0 + 0) * XD + d], wx, ax0);   // uniform -> s_load
        ax1 = fmaf(x[(r0 + 1) * XD + d], wx, ax1);
        ax2 = fmaf(x[(r0 + 2) * XD + d], wx, ax2);
        ax3 = fmaf(x[(r0 + 3) * XD + d], wx, ax3);
        ay0 = fmaf(y[(r0 + 0) * XD + d], wy, ay0);
        ay1 = fmaf(y[(r0 + 1) * XD + d], wy, ay1);
        ay2 = fmaf(y[(r0 + 2) * XD + d], wy, ay2);
        ay3 = fmaf(y[(r0 + 3) * XD + d], wy, ay3);
    }

    const float bk = b1[k];
    float4 xs4 = make_float4(ax0 + bk, ax1 + bk, ax2 + bk, ax3 + bk);
    float4 ys4 = make_float4(ay0, ay1, ay2, ay3);
    *(float4*)&xpbT[k * N_SAMP + r0] = xs4;  // 16B-aligned (r0 % 4 == 0)
    *(float4*)&ypT [k * N_SAMP + r0] = ys4;
}

// Per-chunk helpers (8 k). All indices compile-time (rule: runtime-indexed
// register arrays spill to scratch). LOAD issues 18 ds_reads into named
// register buffers; COMPUTE consumes a buffer loaded one step earlier, so
// the lgkmcnt waits never drain the pipe.
#define CHUNK_LOAD(XB, YB, W0, W1, kb)                                   \
    {                                                                    \
        _Pragma("unroll")                                                \
        for (int u = 0; u < 8; ++u) {                                    \
            XB[u] = *(const float4*)&xs[(kb) + u][tj4];                  \
            YB[u] = *(const float4*)&ys[(kb) + u][ti4];                  \
        }                                                                \
        W0 = *(const float4*)&wlds[kof + (kb)];                          \
        W1 = *(const float4*)&wlds[kof + (kb) + 4];                      \
    }

#define CHUNK_COMPUTE(XB, YB, W0, W1)                                    \
    {                                                                    \
        const float wv[8] = {W0.x, W0.y, W0.z, W0.w,                     \
                             W1.x, W1.y, W1.z, W1.w};                    \
        _Pragma("unroll")                                                \
        for (int u = 0; u < 8; ++u) {                                    \
            const float xa[4] = {XB[u].x, XB[u].y, XB[u].z, XB[u].w};    \
            const float ya[4] = {YB[u].x, YB[u].y, YB[u].z, YB[u].w};    \
            _Pragma("unroll")                                            \
            for (int a = 0; a < 4; ++a)                                  \
                _Pragma("unroll")                                        \
                for (int b = 0; b < 4; ++b)                              \
                    acc[a][b] = fmaf(fmaxf(ya[a] + xa[b], 0.f),          \
                                     wv[u], acc[a][b]);                  \
        }                                                                \
    }

// Kernel 2: pairwise relu-dot, row-sums of exp, diagonal, + ticket finalize.
//
// r6 post-mortem: VGPR_Count=80 (compiler targeting occupancy our
// 1-block/CU grid never uses) -> a chunk's 18 ds_read results (72 VGPR)
// can't be batched -> load/wait/use serialization at ~120+ cy LDS latency
// with 1 wave/SIMD to hide it; plus a likely-unrolled 51 KB loop body
// thrashing the 32 KB I$. Fixes: __launch_bounds__(256,1) lifts the VGPR
// cap; explicit 2-deep register double-buffer pipelines chunk c+1's loads
// under chunk c's 768 cy of FMAs; #pragma unroll 1 on the pass loop keeps
// the body ~13 KB (I$-resident after pass 0).
__global__ __launch_bounds__(256, 1) void pair_fused(
    const float* __restrict__ ypT, const float* __restrict__ xpbT,
    const float* __restrict__ W2,
    float* __restrict__ S, float* __restrict__ T0s,
    const float* __restrict__ b2, float* __restrict__ out)
{
    __shared__ float xs[64][64];       // [kk][j] 16 KB
    __shared__ float ys[64][64];       // [kk][i] 16 KB
    __shared__ float wlds[HID];        // 1 KB

    const int tid = threadIdx.x;
    const int tj  = tid & 15;
    const int ti  = tid >> 4;
    const int jb  = blockIdx.x * 64;
    const int ib  = blockIdx.y * 64;
    const int j0  = jb + tj * 4;
    const int i0  = ib + ti * 4;
    const int tj4 = tj * 4, ti4 = ti * 4;

    // W2 -> LDS once (64 float4 by threads 0..63); first barrier covers it.
    if (tid < 64) *(float4*)&wlds[tid * 4] = *(const float4*)&W2[tid * 4];

    float acc[4][4];
    #pragma unroll
    for (int a = 0; a < 4; ++a)
        #pragma unroll
        for (int b = 0; b < 4; ++b) acc[a][b] = 0.f;

    #pragma unroll 1
    for (int pass = 0; pass < 4; ++pass) {
        const int kof = pass << 6;             // 0,64,128,192
        if (pass) __syncthreads();             // LDS free before restage

        // Stage both panels: 1024 float4 each, 4 per thread per panel.
        // 16 consecutive lanes cover one 256 B row -> coalesced global
        // reads, contiguous (2-way, free) LDS writes.
        #pragma unroll
        for (int s = 0; s < 4; ++s) {
            const int f  = s * 256 + tid;
            const int kk = f >> 4;
            const int q  = (f & 15) * 4;
            *(float4*)&xs[kk][q] = *(const float4*)&xpbT[(kof + kk) * N_SAMP + jb + q];
            *(float4*)&ys[kk][q] = *(const float4*)&ypT [(kof + kk) * N_SAMP + ib + q];
        }
        __syncthreads();

        // 8 chunks of 8 k, 2-deep register pipeline (A/B buffers).
        float4 xA[8], yA[8], xB[8], yB[8];
        float4 w0A, w1A, w0B, w1B;
        CHUNK_LOAD(xA, yA, w0A, w1A, 0);
        #pragma unroll
        for (int c = 0; c < 8; c += 2) {
            if (c + 1 < 8) CHUNK_LOAD(xB, yB, w0B, w1B, (c + 1) * 8);
            CHUNK_COMPUTE(xA, yA, w0A, w1A);
            if (c + 2 < 8) CHUNK_LOAD(xA, yA, w0A, w1A, (c + 2) * 8);
            if (c + 1 < 8) CHUNK_COMPUTE(xB, yB, w0B, w1B);
        }
    }

    // Row sums of exp over this thread's 4 j's, then across the 16 tj lanes
    // (contiguous within a wave), then one atomic per i per block.
    // |acc| ~ O(1): exp without max-shift is safe in f32.
    #pragma unroll
    for (int a = 0; a < 4; ++a) {
        float e = __expf(acc[a][0]) + __expf(acc[a][1])
                + __expf(acc[a][2]) + __expf(acc[a][3]);
        #pragma unroll
        for (int off = 8; off; off >>= 1) e += __shfl_xor(e, off, 16);
        if (tj == 0) atomicAdd(&S[i0 + a], e);
    }

    // Diagonal (T0): 64x64 tiles -> diag blocks are blockIdx.x == blockIdx.y;
    // there, i0+a == j0+b  <=>  ti == tj && a == b.
    if (blockIdx.x == blockIdx.y) {
        float dv = 0.f;
        if (ti == tj)
            dv = acc[0][0] + acc[1][1] + acc[2][2] + acc[3][3];
        #pragma unroll
        for (int off = 32; off; off >>= 1) dv += __shfl_xor(dv, off, 64);
        if ((tid & 63) == 0) atomicAdd(&T0s[0], dv);
    }

    // ---- last-block-done finalize (saves a 3rd kernel launch) ----
    // No spin loops: deadlock-free. Ticket re-zeroed by gemm_xy every
    // replay. All S/T0 traffic is device-scope atomics; read back via
    // atomicAdd(p, 0.f) so values come from the coherence point.
    int* lastflag = (int*)&ys[0][0];           // reuse LDS
    __threadfence();                           // my atomics visible device-wide
    __syncthreads();                           // all lanes' fences done
    if (tid == 0)
        *lastflag = (atomicAdd((unsigned*)&T0s[1], 1u) == 255u);
    __syncthreads();
    if (!*lastflag) return;

    float* red = &xs[0][0];                    // reuse LDS for reduction
    float ls = 0.f;
    for (int i = tid; i < N_SAMP; i += 256)
        ls += logf(atomicAdd(&S[i], 0.f));
    #pragma unroll
    for (int off = 32; off; off >>= 1) ls += __shfl_xor(ls, off, 64);
    if ((tid & 63) == 0) red[tid >> 6] = ls;
    __syncthreads();

    if (tid == 0) {
        const float t0       = atomicAdd(&T0s[0], 0.f);
        const float lse_sum  = red[0] + red[1] + red[2] + red[3];
        const float t0_mean  = t0 / (float)N_SAMP + b2[0];
        const float lse_mean = lse_sum / (float)N_SAMP + b2[0]
                             - logf((float)N_SAMP);
        out[0] = t0_mean - lse_mean;
    }
}

extern "C" void kernel_launch(void* const* d_in, const int* in_sizes, int n_in,
                              void* d_out, int out_size, void* d_ws, size_t ws_size,
                              hipStream_t stream)
{
    const float* x  = (const float*)d_in[0];
    const float* y  = (const float*)d_in[1];
    const float* W1 = (const float*)d_in[2];
    const float* b1 = (const float*)d_in[3];
    const float* W2 = (const float*)d_in[4];
    const float* b2 = (const float*)d_in[5];

    float* ws   = (float*)d_ws;
    float* S    = ws;                          // 1024 floats
    float* T0s  = ws + 1024;                   // [0]=T0sum, [1]=ticket
    float* xpbT = ws + 2048;                   // [HID][N]
    float* ypT  = ws + 2048 + HID * N_SAMP;    // [HID][N]

    gemm_xy   <<<dim3(N_SAMP / 4), dim3(256), 0, stream>>>(x, y, W1, b1,
                                                           xpbT, ypT, S, T0s);
    pair_fused<<<dim3(16, 16),     dim3(256), 0, stream>>>(ypT, xpbT, W2,
                                                           S, T0s, b2,
                                                           (float*)d_out);
}